// Round 5
// baseline (513.866 us; speedup 1.0000x reference)
//
#include <hip/hip_runtime.h>
#include <hip/hip_bf16.h>

// ESA_SMILES fused pipeline for MI355X (gfx950).
// Identity: cap = LN(x)@W1^T+b1 ; feat = cap@W2^T+b2 = LN(x)@(W2W1)^T+(W2b1+b2)
// out[b,d] = sum_n exp(feat[n,d])*cap[n,d] / sum_n exp(feat[n,d])
//
// R10: occupancy restructure (TLP was the binding constraint, not scheduling):
//  - R9 post-mortem: 32x32 dual-GEMM only affords 4 acc chains -> dependency
//    bubble every iteration (135cy issue < dep latency). 16x16 gives 16
//    chains, bubble-free. Reverted to the 16x16 path permanently.
//  - Blocks now cover 48 rows: LDS 48KB -> 3 blocks/CU -> 6 waves/SIMD
//    (+50% TLP to overlap the matrix/DS/VALU pipes that R5 left alternating).
//  - Register cap 512/6 = 85 via __launch_bounds__(512,6): acc shrunk to 48
//    (3mt x 2nt x 2mats), wave does TWO col-passes of 32 cols (A:MFMA ratio
//    unchanged vs R5; B read once per block either way).
//  - No manual prefetch / setprio (R7 proved null). Falsifier: WRITE_SIZE
//    >> 10MB means the 85-reg cap spilled.

#define ROWS 48

typedef short short8 __attribute__((ext_vector_type(8)));   // 8 x bf16
typedef short short4v __attribute__((ext_vector_type(4)));
typedef float f32x4 __attribute__((ext_vector_type(4)));

__device__ inline short f2bf(float f) {
    unsigned u = __float_as_uint(f);
    u += 0x7fffu + ((u >> 16) & 1u);     // round-to-nearest-even
    return (short)(u >> 16);
}

// packed offset for element (n, k) of a 512x512 weight matrix in the
// B-fragment order of mfma_f32_16x16x32_bf16 (R5-verified):
//   t = n>>4, k0 = k>>5, lane = ((k>>3)&3)*16 + (n&15), j = k&7
__device__ inline size_t packed_off(int n, int k) {
    const int t = n >> 4, l16n = n & 15;
    const int k0 = k >> 5, quad = (k >> 3) & 3, j = k & 7;
    return ((size_t)((t * 16 + k0) * 64 + quad * 16 + l16n)) * 8 + j;
}

// ---------------------------------------------------------------------------
// prep_all: ONE dispatch, role-split blocks (512 threads each):
//   blocks 0..63    : W12p = bf16(W2) @ bf16(W1) via MFMA -> packed layout
//   blocks 64..191  : W1 fp32 -> bf16, packed layout (W1p)
//   blocks 192..195 : b12 = W2@b1 + b2 (4 blocks x 128 rows, 4 thr/row)
//   block  196      : entries, 48-row chunks (binary search on data_batch)
//   blocks 197..228 : zero num/den
// ---------------------------------------------------------------------------
#define PREP_GRID 229

__global__ __launch_bounds__(512)
void esa_prep_all(const float* __restrict__ W1, const float* __restrict__ W2,
                  const float* __restrict__ b1, const float* __restrict__ b2,
                  const int* __restrict__ db, int T, int B,
                  short* __restrict__ W1p, short* __restrict__ W12p,
                  float* __restrict__ b12, int4* __restrict__ entries, int maxent,
                  float* __restrict__ numden) {
    __shared__ int off[513];
    __shared__ int nch[512];
    __shared__ int scan[513];
    const int bid = blockIdx.x;
    const int tid = threadIdx.x;

    if (bid < 64) {
        // ---- W12 tile (64x64) via MFMA, converting fp32->bf16 on the fly
        const int ti = bid >> 3, tj = bid & 7;
        const int wave = tid >> 6;          // 0..7
        const int lane = tid & 63;
        const int quad = lane >> 4;
        const int l16 = lane & 15;
        const int mhalf = wave >> 2;        // rows half (m-tiles 0-1 or 2-3)
        const int kq = wave & 3;
        const int kcol = tj * 64 + kq * 16 + l16;

        f32x4 acc[2];
        acc[0] = (f32x4)0.0f; acc[1] = (f32x4)0.0f;
        for (int j0 = 0; j0 < 512; j0 += 32) {
            short8 bfr;
#pragma unroll
            for (int jj = 0; jj < 8; ++jj)
                bfr[jj] = f2bf(W1[(size_t)(j0 + quad * 8 + jj) * 512 + kcol]);
#pragma unroll
            for (int mt = 0; mt < 2; ++mt) {
                const float* ar = W2 + (size_t)(ti * 64 + (mhalf * 2 + mt) * 16 + l16) * 512 +
                                  j0 + quad * 8;
                const float4 a0 = *(const float4*)ar;
                const float4 a1 = *(const float4*)(ar + 4);
                short8 afr = {f2bf(a0.x), f2bf(a0.y), f2bf(a0.z), f2bf(a0.w),
                              f2bf(a1.x), f2bf(a1.y), f2bf(a1.z), f2bf(a1.w)};
                acc[mt] = __builtin_amdgcn_mfma_f32_16x16x32_bf16(afr, bfr,
                                                                  acc[mt], 0, 0, 0);
            }
        }
        // C/D layout: col(k) = lane&15, row(n) = quad*4 + r -> packed store
#pragma unroll
        for (int mt = 0; mt < 2; ++mt)
#pragma unroll
            for (int r = 0; r < 4; ++r) {
                const int n = ti * 64 + (mhalf * 2 + mt) * 16 + quad * 4 + r;
                W12p[packed_off(n, kcol)] = f2bf(acc[mt][r]);
            }
    } else if (bid < 192) {
        // ---- W1 -> bf16, packed. 4 consecutive k share a packed short4 slot.
        const int gid = (bid - 64) * 512 + tid;
        const int i4 = gid * 4;
        const int n = i4 >> 9, k = i4 & 511;
        const float4 a = *(const float4*)(W1 + i4);
        short4v sa = {f2bf(a.x), f2bf(a.y), f2bf(a.z), f2bf(a.w)};
        *(short4v*)(W1p + packed_off(n, k)) = sa;
    } else if (bid < 196) {
        // ---- b12 = W2@b1 + b2 : 4 blocks x 128 rows, 4 threads per row
        const int row = (bid - 192) * 128 + (tid >> 2);
        const int part = tid & 3;
        const float* wr = W2 + (size_t)row * 512;
        float acc = 0.0f;
#pragma unroll 4
        for (int i = 0; i < 32; ++i) {
            const float4 w = *(const float4*)(wr + (i * 4 + part) * 4);
            const float4 bb = *(const float4*)(b1 + (i * 4 + part) * 4);
            acc += w.x * bb.x + w.y * bb.y + w.z * bb.z + w.w * bb.w;
        }
        acc += __shfl_xor(acc, 1);
        acc += __shfl_xor(acc, 2);
        if (part == 0) b12[row] = acc + b2[row];
    } else if (bid == 196) {
        // ---- entries (48-row chunks)
        for (int t = tid; t <= B; t += 512) {
            if (t == B) {
                off[t] = T;
            } else {
                int lo = 0, hi = T;
                while (lo < hi) {
                    int mid = (lo + hi) >> 1;
                    if (db[mid] < t) lo = mid + 1; else hi = mid;
                }
                off[t] = lo;
            }
        }
        __syncthreads();
        for (int t = tid; t < B; t += 512)
            nch[t] = (off[t + 1] - off[t] + (ROWS - 1)) / ROWS;
        __syncthreads();
        if (tid == 0) {
            int s = 0;
            for (int i = 0; i < B; ++i) { scan[i] = s; s += nch[i]; }
            scan[B] = s;
        }
        __syncthreads();
        for (int t = tid; t < B; t += 512) {
            int cnt = off[t + 1] - off[t];
            for (int j = 0; j < nch[t]; ++j) {
                int v = cnt - j * ROWS;
                if (v > ROWS) v = ROWS;
                entries[scan[t] + j] = make_int4(t, off[t] + j * ROWS, v, 0);
            }
        }
        int total = scan[B];
        for (int i = total + tid; i < maxent; i += 512)
            entries[i] = make_int4(0, 0, 0, 0);
    } else {
        // ---- zero num/den (2*B*512 floats = 131072)
        const int idx = (bid - 197) * 512 + tid;   // 0..16383
        float4 z = {0.0f, 0.0f, 0.0f, 0.0f};
        *(float4*)(numden + (size_t)idx * 8) = z;
        *(float4*)(numden + (size_t)idx * 8 + 4) = z;
    }
}

// ---------------------------------------------------------------------------
// Main fused kernel: one block = 48 nodes of one batch, 512 threads (8 waves),
// LDS 48KB -> 3 blocks/CU -> 24 waves/CU (6/SIMD). Fresh blocks, grid=maxent.
// Phase 1: LayerNorm, rows wave*6..+5 in two 3-row ILP groups, XOR-swizzled
//   LDS store (R5 layout).
// Phase 2: TWO col-passes; per pass the wave owns 32 cols (2 nt-tiles):
//   per k0: 3 A ds_read_b128 + 4 packed 1KB B loads + 12 MFMA (12 acc chains
//   x 19.4cy = 233cy between dependent issues -> bubble-free).
// Epilogue per pass: e=exp(feat); column sums; 2 atomics/col.
// ---------------------------------------------------------------------------
__global__ __launch_bounds__(512, 6)
void esa_fused(const float* __restrict__ x, const float* __restrict__ gamma,
               const float* __restrict__ beta, const short* __restrict__ W1p,
               const short* __restrict__ W12p, const float* __restrict__ b1,
               const float* __restrict__ b12, const int4* __restrict__ entries,
               float* __restrict__ num, float* __restrict__ den) {
    __shared__ short ylds[ROWS * 512];   // 49,152 B -> 3 blocks/CU
    const int4 e = entries[blockIdx.x];
    const int bat = e.x, start = e.y, valid = e.z;
    if (valid <= 0) return;

    const int tid = threadIdx.x;
    const int wave = tid >> 6;          // 0..7
    const int lane = tid & 63;
    const int quad = lane >> 4;
    const int l16 = lane & 15;

    // ---- Phase 1: LayerNorm, rows wave*6..+5, lane owns 8 cols. Branch-free.
    const float4 g0 = *(const float4*)(gamma + lane * 8);
    const float4 g1 = *(const float4*)(gamma + lane * 8 + 4);
    const float4 be0 = *(const float4*)(beta + lane * 8);
    const float4 be1 = *(const float4*)(beta + lane * 8 + 4);

#pragma unroll
    for (int g = 0; g < 2; ++g) {               // two ILP groups of 3 rows
        float4 ra[3], rb[3];
        float s[3], ss[3];
#pragma unroll
        for (int r = 0; r < 3; ++r) {
            const int m = wave * 6 + g * 3 + r;
            const int mc = m < valid ? m : valid - 1;   // clamp: always in-batch
            const float* xr_ = x + (size_t)(start + mc) * 512 + lane * 8;
            ra[r] = *(const float4*)xr_;
            rb[r] = *(const float4*)(xr_ + 4);
        }
#pragma unroll
        for (int r = 0; r < 3; ++r) {
            s[r] = ra[r].x + ra[r].y + ra[r].z + ra[r].w +
                   rb[r].x + rb[r].y + rb[r].z + rb[r].w;
            ss[r] = ra[r].x * ra[r].x + ra[r].y * ra[r].y + ra[r].z * ra[r].z +
                    ra[r].w * ra[r].w + rb[r].x * rb[r].x + rb[r].y * rb[r].y +
                    rb[r].z * rb[r].z + rb[r].w * rb[r].w;
        }
#pragma unroll
        for (int o = 1; o <= 32; o <<= 1) {     // 3 interleaved chains
#pragma unroll
            for (int r = 0; r < 3; ++r) {
                s[r] += __shfl_xor(s[r], o);
                ss[r] += __shfl_xor(ss[r], o);
            }
        }
#pragma unroll
        for (int r = 0; r < 3; ++r) {
            const int m = wave * 6 + g * 3 + r;
            const float mu = s[r] * (1.0f / 512.0f);
            const float var = ss[r] * (1.0f / 512.0f) - mu * mu;
            const float rstd = rsqrtf(var + 1e-5f);
            short8 outv;
            outv[0] = f2bf((ra[r].x - mu) * rstd * g0.x + be0.x);
            outv[1] = f2bf((ra[r].y - mu) * rstd * g0.y + be0.y);
            outv[2] = f2bf((ra[r].z - mu) * rstd * g0.z + be0.z);
            outv[3] = f2bf((ra[r].w - mu) * rstd * g0.w + be0.w);
            outv[4] = f2bf((rb[r].x - mu) * rstd * g1.x + be1.x);
            outv[5] = f2bf((rb[r].y - mu) * rstd * g1.y + be1.y);
            outv[6] = f2bf((rb[r].z - mu) * rstd * g1.z + be1.z);
            outv[7] = f2bf((rb[r].w - mu) * rstd * g1.w + be1.w);
            // XOR swizzle: column-block lane stored at lane ^ (m&7)
            *(short8*)&ylds[m * 512 + ((lane ^ (m & 7)) * 8)] = outv;
        }
    }
    __syncthreads();

    // ---- Phase 2: dual GEMM (16x16x32) + epilogue, TWO 32-col passes.
    const int xr7 = l16 & 7;
    const short* abase = ylds + l16 * 512;
    const bool full = (valid >= ROWS);

#pragma unroll 1
    for (int pass = 0; pass < 2; ++pass) {
        const int nt0 = pass * 16 + wave * 2;   // 16-col tile base, 0..31
        const short* w1a = W1p + (size_t)nt0 * 8192 + lane * 8;
        const short* w1b = w1a + 8192;
        const short* w2a = W12p + (size_t)nt0 * 8192 + lane * 8;
        const short* w2b = w2a + 8192;

        f32x4 acc_c[2][3], acc_f[2][3];         // [nt][mt] : 12 chains, 48 regs
#pragma unroll
        for (int nt = 0; nt < 2; ++nt)
#pragma unroll
            for (int mt = 0; mt < 3; ++mt) {
                acc_c[nt][mt] = (f32x4)0.0f;
                acc_f[nt][mt] = (f32x4)0.0f;
            }

#pragma unroll 1
        for (int k0 = 0; k0 < 16; ++k0) {
            // swizzled A-frag address: column block (4k0+quad) ^ (l16&7)
            const int blk = ((k0 << 2) | quad) ^ xr7;
            const short* ap = abase + blk * 8;
            const short8 af0 = *(const short8*)(ap);
            const short8 af1 = *(const short8*)(ap + 16 * 512);
            const short8 af2 = *(const short8*)(ap + 32 * 512);
            const short8 b10 = *(const short8*)(w1a + k0 * 512);
            const short8 b11 = *(const short8*)(w1b + k0 * 512);
            const short8 b20 = *(const short8*)(w2a + k0 * 512);
            const short8 b21 = *(const short8*)(w2b + k0 * 512);
            acc_c[0][0] = __builtin_amdgcn_mfma_f32_16x16x32_bf16(af0, b10, acc_c[0][0], 0, 0, 0);
            acc_c[0][1] = __builtin_amdgcn_mfma_f32_16x16x32_bf16(af1, b10, acc_c[0][1], 0, 0, 0);
            acc_c[0][2] = __builtin_amdgcn_mfma_f32_16x16x32_bf16(af2, b10, acc_c[0][2], 0, 0, 0);
            acc_c[1][0] = __builtin_amdgcn_mfma_f32_16x16x32_bf16(af0, b11, acc_c[1][0], 0, 0, 0);
            acc_c[1][1] = __builtin_amdgcn_mfma_f32_16x16x32_bf16(af1, b11, acc_c[1][1], 0, 0, 0);
            acc_c[1][2] = __builtin_amdgcn_mfma_f32_16x16x32_bf16(af2, b11, acc_c[1][2], 0, 0, 0);
            acc_f[0][0] = __builtin_amdgcn_mfma_f32_16x16x32_bf16(af0, b20, acc_f[0][0], 0, 0, 0);
            acc_f[0][1] = __builtin_amdgcn_mfma_f32_16x16x32_bf16(af1, b20, acc_f[0][1], 0, 0, 0);
            acc_f[0][2] = __builtin_amdgcn_mfma_f32_16x16x32_bf16(af2, b20, acc_f[0][2], 0, 0, 0);
            acc_f[1][0] = __builtin_amdgcn_mfma_f32_16x16x32_bf16(af0, b21, acc_f[1][0], 0, 0, 0);
            acc_f[1][1] = __builtin_amdgcn_mfma_f32_16x16x32_bf16(af1, b21, acc_f[1][1], 0, 0, 0);
            acc_f[1][2] = __builtin_amdgcn_mfma_f32_16x16x32_bf16(af2, b21, acc_f[1][2], 0, 0, 0);
        }

        // Epilogue: C/D layout col=lane&15, row=quad*4+reg (m89-verified)
#pragma unroll
        for (int nt = 0; nt < 2; ++nt) {
            const int n = pass * 256 + wave * 32 + nt * 16 + l16;
            const float bb1 = b1[n];
            const float bb2 = b12[n];
            float se = 0.0f, sec = 0.0f;
            if (full) {
                // wave-uniform fast path: every row valid, no compares
#pragma unroll
                for (int mt = 0; mt < 3; ++mt) {
#pragma unroll
                    for (int r2 = 0; r2 < 4; ++r2) {
                        const float cap = acc_c[nt][mt][r2] + bb1;
                        const float ev = __expf(acc_f[nt][mt][r2] + bb2);
                        se += ev;
                        sec += ev * cap;
                    }
                }
            } else {
#pragma unroll
                for (int mt = 0; mt < 3; ++mt) {
#pragma unroll
                    for (int r2 = 0; r2 < 4; ++r2) {
                        const int m = mt * 16 + quad * 4 + r2;
                        if (m < valid) {
                            const float cap = acc_c[nt][mt][r2] + bb1;
                            const float ev = __expf(acc_f[nt][mt][r2] + bb2);
                            se += ev;
                            sec += ev * cap;
                        }
                    }
                }
            }
            se += __shfl_xor(se, 16);
            se += __shfl_xor(se, 32);
            sec += __shfl_xor(sec, 16);
            sec += __shfl_xor(sec, 32);
            if (quad == 0) atomicAdd(&den[(size_t)bat * 512 + n], se);
            else if (quad == 1) atomicAdd(&num[(size_t)bat * 512 + n], sec);
        }
    }
}

__global__ __launch_bounds__(256)
void esa_finalize(const float* __restrict__ num, const float* __restrict__ den,
                  float* __restrict__ out, int n) {
    const int i = blockIdx.x * 256 + threadIdx.x;
    if (i < n) {
        const float d = den[i];
        out[i] = d > 0.0f ? num[i] / d : 0.0f;
    }
}

extern "C" void kernel_launch(void* const* d_in, const int* in_sizes, int n_in,
                              void* d_out, int out_size, void* d_ws, size_t ws_size,
                              hipStream_t stream) {
    const float* x = (const float*)d_in[0];
    const int* db = (const int*)d_in[1];
    // d_in[2] = max_nodes (unused: chunking derived from actual counts)
    const float* gamma = (const float*)d_in[3];
    const float* beta = (const float*)d_in[4];
    const float* W1 = (const float*)d_in[5];
    const float* b1 = (const float*)d_in[6];
    const float* W2 = (const float*)d_in[7];
    const float* b2 = (const float*)d_in[8];
    float* out = (float*)d_out;

    const int C = in_sizes[3];        // 512
    const int D = in_sizes[6];        // 512
    const int T = in_sizes[0] / C;    // 131072
    const int B = out_size / D;       // 128
    const int maxent = B + (T + ROWS - 1) / ROWS;   // 128 + 2731 = 2859

    char* ws = (char*)d_ws;
    short* W1p = (short*)(ws);                      // 512 KB packed
    short* W12p = (short*)(ws + 524288);            // 512 KB packed
    float* b12 = (float*)(ws + 1048576);            // 2 KB
    int4* entries = (int4*)(ws + 1050624);          // maxent*16
    size_t numoff = (1050624 + (size_t)maxent * 16 + 255) & ~(size_t)255;
    float* num = (float*)(ws + numoff);             // B*D*4
    float* den = (float*)(ws + numoff + (size_t)B * D * 4);

    esa_prep_all<<<PREP_GRID, 512, 0, stream>>>(W1, W2, b1, b2, db, T, B,
                                                W1p, W12p, b12, entries, maxent,
                                                num);
    esa_fused<<<maxent, 512, 0, stream>>>(x, gamma, beta, W1p, W12p, b1, b12,
                                          entries, num, den);
    esa_finalize<<<(B * D + 255) / 256, 256, 0, stream>>>(num, den, out, B * D);
}